// Round 6
// baseline (134.855 us; speedup 1.0000x reference)
//
#include <hip/hip_runtime.h>
#include <hip/hip_bf16.h>

typedef __attribute__((ext_vector_type(4))) float f32x4;
typedef __attribute__((ext_vector_type(8))) short bf16x8;
typedef __attribute__((ext_vector_type(2))) unsigned int u32x2;
typedef unsigned short u16;
typedef unsigned int u32;

// ---------- helpers ----------

__device__ __forceinline__ u16 f2bf(float f) {
  union { float f; unsigned int u; } v;
  v.f = f;
  unsigned int r = (v.u + 0x7fffu + ((v.u >> 16) & 1u)) >> 16;
  return (u16)r;
}

__device__ __forceinline__ u32 pk2(float a, float b) {
  u32 r;
  asm("v_cvt_pk_bf16_f32 %0, %1, %2" : "=v"(r) : "v"(a), "v"(b));
  return r;
}

// async global->LDS, 16 bytes/lane; LDS dest = wave-uniform base + lane*16
__device__ __forceinline__ void async16(const void* g, const void* l) {
  __builtin_amdgcn_global_load_lds(
      (const __attribute__((address_space(1))) unsigned int*)(unsigned long)g,
      (__attribute__((address_space(3))) unsigned int*)(unsigned int)(unsigned long)l,
      16, 0, 0);
}

__device__ __forceinline__ void bar() {
  asm volatile("" ::: "memory");
  __builtin_amdgcn_s_barrier();
  asm volatile("" ::: "memory");
}

#define WAIT_LGKM0() asm volatile("s_waitcnt lgkmcnt(0)" ::: "memory")
#define WAIT_VM0()   asm volatile("s_waitcnt vmcnt(0)" ::: "memory")
#define G8(r) ((((r) >> 3) ^ (r)) & 7)

// ---------- 1) fused K+V transposed convert: fp32 [2048][1024] -> bf16 [1024][2048] ----------

__global__ __launch_bounds__(256) void cvt_kv(const float* __restrict__ Kin,
                                              const float* __restrict__ Vin,
                                              u16* __restrict__ Kt,
                                              u16* __restrict__ Vt) {
  __shared__ u16 tile[64][68];
  const int z = blockIdx.z;           // 0..15: batch = z>>1, tensor = z&1
  const int bsel = z >> 1;
  const float* in = (z & 1) ? Kin : Vin;
  u16* out = (z & 1) ? Kt : Vt;
  const long bo = (long)bsel * 2048 * 1024;
  const int r0 = blockIdx.y * 64;     // n
  const int c0 = blockIdx.x * 64;     // h/d
  const int t = threadIdx.x;
  const int tr = t >> 4;
  const int tc4 = (t & 15) * 4;

#pragma unroll
  for (int i = 0; i < 4; ++i) {
    int r = i * 16 + tr;
    f32x4 v = *(const f32x4*)(in + bo + (long)(r0 + r) * 1024 + c0 + tc4);
    tile[tc4 + 0][r] = f2bf(v.x);
    tile[tc4 + 1][r] = f2bf(v.y);
    tile[tc4 + 2][r] = f2bf(v.z);
    tile[tc4 + 3][r] = f2bf(v.w);
  }
  __syncthreads();
#pragma unroll
  for (int i = 0; i < 4; ++i) {
    int c = i * 16 + tr;
    ushort4 u = *(const ushort4*)(&tile[c][tc4]);
    *(ushort4*)(out + bo + (long)(c0 + c) * 2048 + r0 + tc4) = u;
  }
}

// ===================================================================
// GEMM A: Pt[d][h] = sum_n Vt[d][n] * Kt[h][n]  (bf16 NT)
// per batch: M=1024(d) N=1024(h) K=2048(n). BM=256, BN=128, BK=64.
// 512 thr = 8 waves (2M x 4N), per-wave 128x32. Both operands staged via
// global_load_lds (pre-swizzled source, linear LDS). One barrier per K-tile.
// ===================================================================
__global__ __launch_bounds__(512, 2) void gemmA(const u16* __restrict__ Vt,
                                                const u16* __restrict__ Kt,
                                                u16* __restrict__ Pt) {
  __shared__ u16 As[2][256][64];  // 64 KB
  __shared__ u16 Bs[2][128][64];  // 32 KB

  const int bid = blockIdx.x;
  const int b = bid & 7;              // batch -> XCD pin
  const int tile = bid >> 3;          // 0..31
  const int bn0 = (tile & 7) * 128;   // h
  const int bm0 = (tile >> 3) * 256;  // d

  const int tid = threadIdx.x;
  const int lane = tid & 63;
  const int wave = tid >> 6;
  const int wr = wave >> 2;  // 0..1 (M)
  const int wc = wave & 3;   // 0..3 (N)
  const int l16 = lane & 15;
  const int kh = lane >> 4;

  const char* Ab = (const char*)(Vt + (long)b * 1024 * 2048);
  const char* Bb = (const char*)(Kt + (long)b * 1024 * 2048);

  // staging offsets (pre-swizzled global source, linear LDS dest)
  int aoff[4], boff[2];
#pragma unroll
  for (int i = 0; i < 4; ++i) {
    int u = tid + i * 512;                       // 0..2047
    int row = u >> 3, sl = (u & 7) ^ (row & 7);
    aoff[i] = (bm0 + row) * 4096 + sl * 16;      // row stride 2048*2B
  }
#pragma unroll
  for (int i = 0; i < 2; ++i) {
    int u = tid + i * 512;                       // 0..1023
    int row = u >> 3, sl = (u & 7) ^ (row & 7);
    boff[i] = (bn0 + row) * 4096 + sl * 16;
  }

#define STG_A(buf)                                                          \
  {                                                                         \
    _Pragma("unroll") for (int i_ = 0; i_ < 4; ++i_) {                      \
      async16(Ab + aoff[i_], (char*)&As[buf][0][0] + (tid + i_ * 512) * 16);\
      aoff[i_] += 128;                                                      \
    }                                                                       \
  }
#define STG_B(buf)                                                          \
  {                                                                         \
    _Pragma("unroll") for (int i_ = 0; i_ < 2; ++i_) {                      \
      async16(Bb + boff[i_], (char*)&Bs[buf][0][0] + (tid + i_ * 512) * 16);\
      boff[i_] += 128;                                                      \
    }                                                                       \
  }

  // fragment read offsets (elements); row&7 == l16&7 for all fragment rows
  int offA[2][4][2];  // [qm][f][ks]
#pragma unroll
  for (int q = 0; q < 2; ++q)
#pragma unroll
    for (int f = 0; f < 4; ++f) {
      int r = q * 128 + wr * 64 + f * 16 + l16;
#pragma unroll
      for (int ks = 0; ks < 2; ++ks)
        offA[q][f][ks] = r * 64 + (((ks * 4 + kh) ^ (l16 & 7)) * 8);
    }
  int offB[2][2];  // [fn][ks]
#pragma unroll
  for (int fn = 0; fn < 2; ++fn) {
    int r = fn * 64 + wc * 16 + l16;
#pragma unroll
    for (int ks = 0; ks < 2; ++ks)
      offB[fn][ks] = r * 64 + (((ks * 4 + kh) ^ (l16 & 7)) * 8);
  }

  f32x4 acc[8][2] = {};
  bf16x8 ar[4][2], br[2][2];

  // prologue: stage tile 0
  STG_A(0); STG_B(0);
  WAIT_VM0();
  bar();

  const int NT = 32;
  for (int t = 0; t < NT; ++t) {
    const int cur = t & 1, nxt = cur ^ 1;
    const bool g = (t + 1 < NT);
    const u16* Abuf = &As[cur][0][0];
    const u16* Bbuf = &Bs[cur][0][0];

    // reads: A half0 + all B
#pragma unroll
    for (int f = 0; f < 4; ++f)
#pragma unroll
      for (int ks = 0; ks < 2; ++ks)
        ar[f][ks] = *(const bf16x8*)(Abuf + offA[0][f][ks]);
#pragma unroll
    for (int fn = 0; fn < 2; ++fn)
#pragma unroll
      for (int ks = 0; ks < 2; ++ks)
        br[fn][ks] = *(const bf16x8*)(Bbuf + offB[fn][ks]);

    // issue next-tile staging
    if (g) { STG_A(nxt); STG_B(nxt); }

    // MMA half 0 (16 MFMA)
    __builtin_amdgcn_s_setprio(1);
#pragma unroll
    for (int f = 0; f < 4; ++f)
#pragma unroll
      for (int n = 0; n < 2; ++n)
#pragma unroll
        for (int ks = 0; ks < 2; ++ks)
          acc[f][n] = __builtin_amdgcn_mfma_f32_16x16x32_bf16(
              ar[f][ks], br[n][ks], acc[f][n], 0, 0, 0);
    __builtin_amdgcn_s_setprio(0);

    // reads: A half1
#pragma unroll
    for (int f = 0; f < 4; ++f)
#pragma unroll
      for (int ks = 0; ks < 2; ++ks)
        ar[f][ks] = *(const bf16x8*)(Abuf + offA[1][f][ks]);

    // MMA half 1
    __builtin_amdgcn_s_setprio(1);
#pragma unroll
    for (int f = 0; f < 4; ++f)
#pragma unroll
      for (int n = 0; n < 2; ++n)
#pragma unroll
        for (int ks = 0; ks < 2; ++ks)
          acc[4 + f][n] = __builtin_amdgcn_mfma_f32_16x16x32_bf16(
              ar[f][ks], br[n][ks], acc[4 + f][n], 0, 0, 0);
    __builtin_amdgcn_s_setprio(0);

    if (g) WAIT_VM0();  // staged tile resident before next iteration's reads
    bar();
  }
#undef STG_A
#undef STG_B

  // epilogue: C/D col = l16, row = kh*4 + r
  u16* Cb = Pt + (long)b * 1024 * 1024;
#pragma unroll
  for (int fm = 0; fm < 8; ++fm) {
    const int gm = bm0 + (fm >> 2) * 128 + wr * 64 + (fm & 3) * 16 + kh * 4;
#pragma unroll
    for (int fn = 0; fn < 2; ++fn) {
      const int gn = bn0 + fn * 64 + wc * 16 + l16;
#pragma unroll
      for (int r = 0; r < 4; ++r)
        Cb[(long)(gm + r) * 1024 + gn] = f2bf(acc[fm][fn][r]);
    }
  }
}

// ===================================================================
// GEMM B (fused convert): out[m][d] = sum_h Q[m][h] * Pt[d][h]
// (unchanged from R5 — measured ~24 us)
// ===================================================================
__global__ __launch_bounds__(512, 2) void gemmB(const float* __restrict__ Q,
                                                const u16* __restrict__ Pt,
                                                float* __restrict__ out) {
  __shared__ u16 As[2][256][64];      // Q tile, 64 KB
  __shared__ u16 Bs[2][2][128][64];   // Pt tile halves, 64 KB

  const int bid = blockIdx.x;
  const int b = bid & 7;
  const int tile = bid >> 3;              // 0..31
  const int bn0 = (tile & 3) * 256;       // d
  const int bm0 = (tile >> 2) * 256;      // m

  const int tid = threadIdx.x;
  const int lane = tid & 63;
  const int wave = tid >> 6;
  const int wr = wave >> 2;  // 0..1
  const int wc = wave & 3;   // 0..3
  const int l16 = lane & 15;
  const int kh = lane >> 4;

  const int mrow = tid >> 4;          // 0..31
  const char* pQ = (const char*)(Q + (long)b * 2048 * 1024 +
                                 (long)(bm0 + mrow) * 1024 + (tid & 15) * 4);

  int qwo[8];
#pragma unroll
  for (int p = 0; p < 8; ++p) {
    int r = p * 32 + mrow;
    qwo[p] = r * 128 + ((((tid & 15) >> 1) ^ G8(r)) * 16) + (tid & 1) * 8;
  }

  int boff[2][2];
#pragma unroll
  for (int h = 0; h < 2; ++h)
#pragma unroll
    for (int i = 0; i < 2; ++i) {
      int u = tid + i * 512;
      int row = u >> 3, sl = (u & 7) ^ (row & 7);
      boff[h][i] = (bn0 + h * 128 + row) * 2048 + sl * 16;
    }
  const char* PtB = (const char*)(Pt + (long)b * 1024 * 1024);

  int offA[2][4][2];
#pragma unroll
  for (int q = 0; q < 2; ++q)
#pragma unroll
    for (int f = 0; f < 4; ++f) {
      int r = q * 128 + wr * 64 + f * 16 + l16;
#pragma unroll
      for (int ks = 0; ks < 2; ++ks)
        offA[q][f][ks] = r * 64 + (((ks * 4 + kh) ^ G8(r)) * 8);
    }
  int offBf[2][2];
#pragma unroll
  for (int g_ = 0; g_ < 2; ++g_) {
    int r = wc * 32 + g_ * 16 + l16;
#pragma unroll
    for (int ks = 0; ks < 2; ++ks)
      offBf[g_][ks] = r * 64 + (((ks * 4 + kh) ^ (l16 & 7)) * 8);
  }

#define STG_PT(h, buf)                                                      \
  {                                                                         \
    _Pragma("unroll") for (int i_ = 0; i_ < 2; ++i_) {                      \
      async16(PtB + boff[h][i_],                                            \
              (char*)&Bs[buf][h][0][0] + (tid + i_ * 512) * 16);            \
      boff[h][i_] += 128;                                                   \
    }                                                                       \
  }

  f32x4 acc[8][4] = {};
  f32x4 qv[8];
  bf16x8 ar[4][2], br[4][2];

#pragma unroll
  for (int p = 0; p < 8; ++p) qv[p] = *(const f32x4*)(pQ + p * 131072);
  STG_PT(0, 0);
  STG_PT(1, 0);
  {
    char* dA = (char*)&As[0][0][0];
#pragma unroll
    for (int p = 0; p < 8; ++p) {
      u32x2 v; v.x = pk2(qv[p].x, qv[p].y); v.y = pk2(qv[p].z, qv[p].w);
      *(u32x2*)(dA + qwo[p]) = v;
    }
  }
  pQ += 256;
  WAIT_VM0();
  WAIT_LGKM0();
  bar();

  const int NT = 16;
  for (int t = 0; t < NT; ++t) {
    const int cur = t & 1, nxt = cur ^ 1;
    const bool g = (t + 1 < NT);
    const u16* Ab = &As[cur][0][0];

#pragma unroll
    for (int f = 0; f < 4; ++f)
#pragma unroll
      for (int ks = 0; ks < 2; ++ks)
        ar[f][ks] = *(const bf16x8*)(Ab + offA[0][f][ks]);
#pragma unroll
    for (int qn = 0; qn < 2; ++qn)
#pragma unroll
      for (int g_ = 0; g_ < 2; ++g_)
#pragma unroll
        for (int ks = 0; ks < 2; ++ks)
          br[qn * 2 + g_][ks] =
              *(const bf16x8*)(&Bs[cur][qn][0][0] + offBf[g_][ks]);

    if (g) {
#pragma unroll
      for (int p = 0; p < 8; ++p) qv[p] = *(const f32x4*)(pQ + p * 131072);
      STG_PT(0, nxt);
      STG_PT(1, nxt);
    }

    __builtin_amdgcn_s_setprio(1);
#pragma unroll
    for (int f = 0; f < 4; ++f)
#pragma unroll
      for (int n = 0; n < 4; ++n)
#pragma unroll
        for (int ks = 0; ks < 2; ++ks)
          acc[f][n] = __builtin_amdgcn_mfma_f32_16x16x32_bf16(
              ar[f][ks], br[n][ks], acc[f][n], 0, 0, 0);
    __builtin_amdgcn_s_setprio(0);

#pragma unroll
    for (int f = 0; f < 4; ++f)
#pragma unroll
      for (int ks = 0; ks < 2; ++ks)
        ar[f][ks] = *(const bf16x8*)(Ab + offA[1][f][ks]);

    if (g) {
      char* dA = (char*)&As[nxt][0][0];
#pragma unroll
      for (int p = 0; p < 8; ++p) {
        u32x2 v; v.x = pk2(qv[p].x, qv[p].y); v.y = pk2(qv[p].z, qv[p].w);
        *(u32x2*)(dA + qwo[p]) = v;
      }
      pQ += 256;
    }

    __builtin_amdgcn_s_setprio(1);
#pragma unroll
    for (int f = 0; f < 4; ++f)
#pragma unroll
      for (int n = 0; n < 4; ++n)
#pragma unroll
        for (int ks = 0; ks < 2; ++ks)
          acc[4 + f][n] = __builtin_amdgcn_mfma_f32_16x16x32_bf16(
              ar[f][ks], br[n][ks], acc[4 + f][n], 0, 0, 0);
    __builtin_amdgcn_s_setprio(0);

    if (g) WAIT_VM0();
    WAIT_LGKM0();
    bar();
  }

  float* Cf = out + (long)b * 2048 * 1024;
#pragma unroll
  for (int fm = 0; fm < 8; ++fm) {
    const int gm = bm0 + (fm >> 2) * 128 + wr * 64 + (fm & 3) * 16 + kh * 4;
#pragma unroll
    for (int fn = 0; fn < 4; ++fn) {
      const int gn = bn0 + (fn >> 1) * 128 + wc * 32 + (fn & 1) * 16 + l16;
#pragma unroll
      for (int r = 0; r < 4; ++r)
        Cf[(long)(gm + r) * 1024 + gn] = acc[fm][fn][r];
    }
  }
#undef STG_PT
}

// ---------- launch ----------

extern "C" void kernel_launch(void* const* d_in, const int* in_sizes, int n_in,
                              void* d_out, int out_size, void* d_ws, size_t ws_size,
                              hipStream_t stream) {
  const float* Q  = (const float*)d_in[0];
  const float* Kf = (const float*)d_in[1];
  // d_in[2] = span   (unused by the reference's returned value)
  const float* V  = (const float*)d_in[3];
  // d_in[4] = key_pe (unused)
  float* out = (float*)d_out;

  // workspace: Vt 32MB, Kt 32MB, Pt 16MB
  char* ws = (char*)d_ws;
  u16* Vt = (u16*)(ws);
  u16* Kt = (u16*)(ws + (size_t)32 * 1024 * 1024);
  u16* Pt = (u16*)(ws + (size_t)64 * 1024 * 1024);

  // 1) K+V transposed convert (one launch, z = batch*2 + tensor)
  cvt_kv<<<dim3(16, 32, 16), 256, 0, stream>>>(Kf, V, Kt, Vt);

  // 2) GEMM A: Pt[d][h] = sum_n Vt[d][n]*Kt[h][n]; 256 blocks
  gemmA<<<256, 512, 0, stream>>>(Vt, Kt, Pt);

  // 3) GEMM B: out[m][d] = sum_h Q[m][h]*Pt[d][h]; 256 blocks
  gemmB<<<256, 512, 0, stream>>>(Q, Pt, out);
}